// Round 3
// baseline (1936.786 us; speedup 1.0000x reference)
//
#include <hip/hip_runtime.h>
#include <hip/hip_bf16.h>

typedef unsigned short u16;
typedef __bf16  bf16x8 __attribute__((ext_vector_type(8)));
typedef float   f32x4  __attribute__((ext_vector_type(4)));

__device__ __constant__ float NF4C[16] = {
    -1.0f, -0.6961928009986877f, -0.5250730514526367f, -0.39491748809814453f,
    -0.28444138169288635f, -0.18477343022823334f, -0.09105003625154495f, 0.0f,
    0.07958029955625534f, 0.16093020141124725f, 0.24611230194568634f,
    0.33791524171829224f, 0.44070982933044434f, 0.5626170039176941f,
    0.7229568362236023f, 1.0f };

__device__ __forceinline__ u16 f2bf(float f) {
    union { float f; unsigned u; } v; v.f = f;
    unsigned r = v.u + 0x7FFFu + ((v.u >> 16) & 1u);
    return (u16)(r >> 16);
}
__device__ __forceinline__ float bf2f(u16 b) {
    union { unsigned u; float f; } v; v.u = ((unsigned)b) << 16;
    return v.f;
}

// async global->LDS, 16 bytes per lane (global_load_lds_dwordx4).
__device__ __forceinline__ void gl2lds16(const void* g, void* l) {
    __builtin_amdgcn_global_load_lds(
        (__attribute__((address_space(1))) void*)g,
        (__attribute__((address_space(3))) void*)l,
        16, 0, 0);
}

#define WAITVM(N) asm volatile("s_waitcnt vmcnt(" #N ")" ::: "memory")
#define SCHED0()  __builtin_amdgcn_sched_barrier(0)
#define BAR()     __builtin_amdgcn_s_barrier()

// ---------------- cast x fp32 -> bf16, 8 elems/thread ----------------
__global__ __launch_bounds__(256) void cast_f32_bf16(
    const float* __restrict__ in, u16* __restrict__ out, int n8) {
    int i = blockIdx.x * 256 + threadIdx.x;
    if (i >= n8) return;
    const float4* p = (const float4*)in + (size_t)i * 2;
    float4 a = p[0], b = p[1];
    union { u16 u[8]; uint4 v; } r;
    r.u[0] = f2bf(a.x); r.u[1] = f2bf(a.y); r.u[2] = f2bf(a.z); r.u[3] = f2bf(a.w);
    r.u[4] = f2bf(b.x); r.u[5] = f2bf(b.y); r.u[6] = f2bf(b.z); r.u[7] = f2bf(b.w);
    ((uint4*)out)[i] = r.v;
}

// ---------------- NF4 dequant: int32 codes -> bf16, 8 elems/thread ----------
__global__ __launch_bounds__(256) void dequant_nf4(
    const int* __restrict__ q, const float* __restrict__ s,
    u16* __restrict__ w, int I, int spr) {
    __shared__ float tab[16];
    if (threadIdx.x < 16) tab[threadIdx.x] = NF4C[threadIdx.x];
    __syncthreads();
    int col = (blockIdx.x * 256 + threadIdx.x) * 8;
    if (col >= I) return;
    int row = blockIdx.y;
    size_t base = (size_t)row * I + col;
    int4 c0 = *(const int4*)(q + base);
    int4 c1 = *(const int4*)(q + base + 4);
    float sc = s[(size_t)row * spr + (col >> 6)];
    union { u16 u[8]; uint4 v; } r;
    r.u[0] = f2bf(tab[c0.x & 15] * sc);
    r.u[1] = f2bf(tab[c0.y & 15] * sc);
    r.u[2] = f2bf(tab[c0.z & 15] * sc);
    r.u[3] = f2bf(tab[c0.w & 15] * sc);
    r.u[4] = f2bf(tab[c1.x & 15] * sc);
    r.u[5] = f2bf(tab[c1.y & 15] * sc);
    r.u[6] = f2bf(tab[c1.z & 15] * sc);
    r.u[7] = f2bf(tab[c1.w & 15] * sc);
    *(uint4*)(w + base) = r.v;
}

// ---------------- bf16 GEMM, B transposed: C[M,N] = A[M,K] * B[N,K]^T -------
// 256x256 tile, BK=64, 8 waves (2M x 4N), per-wave 128x64 out = acc[8][4].
//
// Round-3 change: ds_reads software-pipelined ONE PHASE AHEAD so the LDS
// read pipe drains concurrently with the MFMA clusters (round-2 serialized
// them: LDS 750 + MFMA 512 + sync per phase = measured 1825 cyc/phase).
// Frag sets: afA/afB (A quad 0/1, 8 regs each), bfA/bfB (B quad 0/1, 4 each).
// Per tile T (buf c=T&1, o=c^1), ONE barrier per phase:
//   P1: issue bfB(c) reads + STG A1(T+1)->o | BAR | MFMA Q00 (afA,bfA)
//   P2: issue afB(c) reads + STG B1(T+1)->o | BAR | MFMA Q01 (afA,bfB)
//   P3:                      STG A0(T+2)->c | BAR | MFMA Q10 (afB,bfA)
//   P4: STG B0(T+2)->c ; vmcnt(2)           | BAR | issue afA/bfA(o) reads
//                                                   (next tile) ; MFMA Q11
// The compiler inserts its own COUNTED lgkmcnt before each cluster (each
// batch gets >=1 full phase + overlaps the intervening MFMA cluster).
// vmcnt(2) at P4 certifies ALL of tile T+1's staging (B1(T+1) + 8 older
// retire; only B0(T+2)'s 2 loads stay in flight) before the P4 barrier
// publishes; the post-barrier reads of buf o are therefore safe.
// WAR (stage-over-read) safety: each STG region's last ds_read batch retires
// at a counted-lgkm wait >=1 barrier before the STG issues (chain verified
// per region). Never drains vmcnt to 0 in the loop.
//
// EPI: 0 = store bf16; 1 = store bf16 silu(gate)*acc (gate may alias Cout);
//      2 = store fp32.
template<int EPI>
__global__ __launch_bounds__(512, 2) void gemm_bt(
    const u16* __restrict__ A, const u16* __restrict__ B,
    void* Cout, const u16* gate, int K, int ldc) {
    __shared__ u16 lA[2 * 16384];   // 64 KB: dbuf x (256 rows x 64 K)
    __shared__ u16 lB[2 * 16384];   // 64 KB

    const int tid  = threadIdx.x;
    const int lane = tid & 63;
    const int wv   = tid >> 6;               // 0..7

    // ---- bijective XCD swizzle (nwg % 8 == 0 for all our launches) ----
    const int NT = gridDim.x, MT = gridDim.y;
    int id  = blockIdx.y * NT + blockIdx.x;
    int nid = (id & 7) * ((NT * MT) >> 3) + (id >> 3);
    const int bx = nid / MT;                 // N tile
    const int by = nid - bx * MT;            // M tile

    // ---- staging lane pattern (16B-granule XOR swizzle, verified 0-conflict)
    const int sr = lane >> 2;                        // row within 16-row group
    const int sq = (lane & 3) ^ ((sr >> 1) & 3);     // swizzled 16B granule

    // band groups owned by this wave (16-row groups, 16 per operand)
    const int gA0 = ((wv & 4) << 1) + (wv & 3);      // A quad0: g 0-3, 8-11
    const int gA1 = gA0 + 4;                         // A quad1: g 4-7, 12-15
    const int gB0 = ((wv >> 1) << 2) + (wv & 1);     // B quad0: g bit1 == 0
    const int gB1 = gB0 + 2;                         // B quad1: g bit1 == 1

    const u16* pA0 = A + (size_t)(by * 256 + gA0 * 16 + sr) * K + (sq << 3);
    const u16* pA1 = A + (size_t)(by * 256 + gA1 * 16 + sr) * K + (sq << 3);
    const u16* pB0 = B + (size_t)(bx * 256 + gB0 * 16 + sr) * K + (sq << 3);
    const u16* pB1 = B + (size_t)(bx * 256 + gB1 * 16 + sr) * K + (sq << 3);

    // LDS stage bases (u16 units): sub-tile (g, kslice s) at (s*16+g)*512
    const int sA0 = gA0 * 512 + lane * 8;
    const int sA1 = gA1 * 512 + lane * 8;
    const int sB0 = gB0 * 512 + lane * 8;
    const int sB1 = gB1 * 512 + lane * 8;

    // fragment read offsets (slot16 = 0..63 permutation, 0 conflicts)
    const int r16    = lane & 15;
    const int pq     = lane >> 4;
    const int slot16 = (r16 << 2) + (pq ^ ((r16 >> 1) & 3));
    const int aBase  = ((wv & 1) << 12) + slot16 * 8;   // (wv&1)*8 groups
    const int bBase  = ((wv >> 1) << 11) + slot16 * 8;  // (wv>>1)*4 groups

#define STG_A0(TT, D) do { const u16* g_ = pA0 + (size_t)(TT) * 64;       \
        u16* l_ = lA + ((D) << 14) + sA0;                                 \
        gl2lds16(g_, l_); gl2lds16(g_ + 32, l_ + 8192); } while (0)
#define STG_A1(TT, D) do { const u16* g_ = pA1 + (size_t)(TT) * 64;       \
        u16* l_ = lA + ((D) << 14) + sA1;                                 \
        gl2lds16(g_, l_); gl2lds16(g_ + 32, l_ + 8192); } while (0)
#define STG_B0(TT, D) do { const u16* g_ = pB0 + (size_t)(TT) * 64;       \
        u16* l_ = lB + ((D) << 14) + sB0;                                 \
        gl2lds16(g_, l_); gl2lds16(g_ + 32, l_ + 8192); } while (0)
#define STG_B1(TT, D) do { const u16* g_ = pB1 + (size_t)(TT) * 64;       \
        u16* l_ = lB + ((D) << 14) + sB1;                                 \
        gl2lds16(g_, l_); gl2lds16(g_ + 32, l_ + 8192); } while (0)

    // A-frag read: DST[mm*2+ks], 8 x ds_read_b128
#define DSR_AF(DST, C_, QM) do {                                          \
        const u16* b_ = lA + ((C_) << 14) + aBase + (QM) * (4 * 512);     \
        _Pragma("unroll")                                                 \
        for (int mm = 0; mm < 4; ++mm) {                                  \
            DST[mm * 2 + 0] = *(const bf16x8*)(b_ + mm * 512);            \
            DST[mm * 2 + 1] = *(const bf16x8*)(b_ + mm * 512 + 8192);     \
        } } while (0)
    // B-frag read: DST[jj*2+ks], 4 x ds_read_b128
#define DSR_BF(DST, C_, QN) do {                                          \
        const u16* b_ = lB + ((C_) << 14) + bBase + (QN) * (2 * 512);     \
        _Pragma("unroll")                                                 \
        for (int jj = 0; jj < 2; ++jj) {                                  \
            DST[jj * 2 + 0] = *(const bf16x8*)(b_ + jj * 512);            \
            DST[jj * 2 + 1] = *(const bf16x8*)(b_ + jj * 512 + 8192);     \
        } } while (0)

#define MFMA_Q(QM, QN, AF, BF) do {                                       \
        __builtin_amdgcn_s_setprio(1);                                    \
        _Pragma("unroll")                                                 \
        for (int mm = 0; mm < 4; ++mm)                                    \
        _Pragma("unroll")                                                 \
        for (int jj = 0; jj < 2; ++jj) {                                  \
            f32x4 c_ = acc[(QM) * 4 + mm][(QN) * 2 + jj];                 \
            c_ = __builtin_amdgcn_mfma_f32_16x16x32_bf16(                 \
                AF[mm * 2 + 0], BF[jj * 2 + 0], c_, 0, 0, 0);             \
            c_ = __builtin_amdgcn_mfma_f32_16x16x32_bf16(                 \
                AF[mm * 2 + 1], BF[jj * 2 + 1], c_, 0, 0, 0);             \
            acc[(QM) * 4 + mm][(QN) * 2 + jj] = c_;                       \
        }                                                                 \
        __builtin_amdgcn_s_setprio(0); } while (0)

    f32x4 acc[8][4] = {};
    bf16x8 afA[8], afB[8], bfA[4], bfB[4];
    const int KT = K >> 6;                   // K-tiles of 64 (>= 2 always)

    // prologue: tile0 fully + tile1 A0/B0; certify tile0; first frag batch
    STG_A0(0, 0); STG_B0(0, 0); STG_A1(0, 0); STG_B1(0, 0);
    STG_A0(1, 1); STG_B0(1, 1);
    WAITVM(4);                               // tile-0's 8 loads retired
    BAR(); SCHED0();
    DSR_AF(afA, 0, 0); DSR_BF(bfA, 0, 0);    // 12 reads in flight

    for (int T = 0; T < KT; ++T) {
        const int c  = T & 1, o = c ^ 1;
        const int t1 = (T + 1 < KT) ? T + 1 : KT - 1;  // clamped (harmless
        const int t2 = (T + 2 < KT) ? T + 2 : KT - 1;  //  dummy re-stage)
        // P1
        DSR_BF(bfB, c, 1);
        STG_A1(t1, o);
        SCHED0(); BAR(); SCHED0();
        MFMA_Q(0, 0, afA, bfA);
        // P2
        DSR_AF(afB, c, 1);
        STG_B1(t1, o);
        SCHED0(); BAR(); SCHED0();
        MFMA_Q(0, 1, afA, bfB);
        // P3
        STG_A0(t2, c);
        SCHED0(); BAR(); SCHED0();
        MFMA_Q(1, 0, afB, bfA);
        // P4
        STG_B0(t2, c);
        WAITVM(2);                           // tile T+1 fully certified
        SCHED0(); BAR(); SCHED0();
        DSR_AF(afA, o, 0); DSR_BF(bfA, o, 0);   // next tile's quad-0 frags
        MFMA_Q(1, 1, afB, bfB);
    }

    // epilogue: D row = (lane>>4)*4 + reg, col = lane&15 (measured m89/m91)
    const int en   = lane & 15;
    const int er   = (lane >> 4) << 2;
    const int row0 = by * 256 + ((wv & 1) << 7);
    const int col0 = bx * 256 + ((wv >> 1) << 6);
    #pragma unroll
    for (int i = 0; i < 8; ++i) {
        int rowb = row0 + i * 16 + er;
        #pragma unroll
        for (int j = 0; j < 4; ++j) {
            int col = col0 + j * 16 + en;
            #pragma unroll
            for (int r = 0; r < 4; ++r) {
                size_t idx = (size_t)(rowb + r) * ldc + col;
                float v = acc[i][j][r];
                if (EPI == 0) {
                    ((u16*)Cout)[idx] = f2bf(v);
                } else if (EPI == 1) {
                    float g = bf2f(gate[idx]);
                    float sg = g / (1.0f + __expf(-g));
                    ((u16*)Cout)[idx] = f2bf(sg * v);
                } else {
                    ((float*)Cout)[idx] = v;
                }
            }
        }
    }
#undef STG_A0
#undef STG_A1
#undef STG_B0
#undef STG_B1
#undef DSR_AF
#undef DSR_BF
#undef MFMA_Q
}

extern "C" void kernel_launch(void* const* d_in, const int* in_sizes, int n_in,
                              void* d_out, int out_size, void* d_ws, size_t ws_size,
                              hipStream_t stream) {
    const float* x   = (const float*)d_in[0];
    const int*   w1q = (const int*)d_in[1];
    const float* w1s = (const float*)d_in[2];
    const int*   w2q = (const int*)d_in[3];
    const float* w2s = (const float*)d_in[4];
    const int*   w3q = (const int*)d_in[5];
    const float* w3s = (const float*)d_in[6];
    float* out = (float*)d_out;

    const int M = 4096, D = 4096, H = 11008;

    u16* xb = (u16*)d_ws;                    // M*D bf16      (33.5 MB)
    u16* wb = xb + (size_t)M * D;            // H*D bf16      (90.2 MB, reused w1/w2/w3)
    u16* hb = wb + (size_t)H * D;            // M*H bf16      (90.2 MB, gate then h)

    // 1. x -> bf16
    cast_f32_bf16<<<(M * D / 8 + 255) / 256, 256, 0, stream>>>(x, xb, M * D / 8);

    // 2-3. w1 dequant, gate = x @ w1^T        grid 43x16 = 688 blocks (%8==0)
    dim3 dqg1((D / 8 + 255) / 256, H);
    dequant_nf4<<<dqg1, 256, 0, stream>>>(w1q, w1s, wb, D, D / 64);
    gemm_bt<0><<<dim3(H / 256, M / 256), 512, 0, stream>>>(xb, wb, hb, nullptr, D, H);

    // 4-5. w2 dequant, h = silu(gate) * (x @ w2^T)   (in-place over gate)
    dequant_nf4<<<dqg1, 256, 0, stream>>>(w2q, w2s, wb, D, D / 64);
    gemm_bt<1><<<dim3(H / 256, M / 256), 512, 0, stream>>>(xb, wb, hb, hb, D, H);

    // 6-7. w3 dequant, out = h @ w3^T (fp32)  grid 16x16 = 256 blocks (%8==0)
    dim3 dqg3((H / 8 + 255) / 256, D);
    dequant_nf4<<<dqg3, 256, 0, stream>>>(w3q, w3s, wb, H, H / 64);
    gemm_bt<2><<<dim3(D / 256, M / 256), 512, 0, stream>>>(hb, wb, out, nullptr, H, D);
}

// Round 4
// 1709.606 us; speedup vs baseline: 1.1329x; 1.1329x over previous
//
#include <hip/hip_runtime.h>
#include <hip/hip_bf16.h>

typedef unsigned short u16;
typedef __bf16  bf16x8 __attribute__((ext_vector_type(8)));
typedef float   f32x4  __attribute__((ext_vector_type(4)));

__device__ __constant__ float NF4C[16] = {
    -1.0f, -0.6961928009986877f, -0.5250730514526367f, -0.39491748809814453f,
    -0.28444138169288635f, -0.18477343022823334f, -0.09105003625154495f, 0.0f,
    0.07958029955625534f, 0.16093020141124725f, 0.24611230194568634f,
    0.33791524171829224f, 0.44070982933044434f, 0.5626170039176941f,
    0.7229568362236023f, 1.0f };

__device__ __forceinline__ u16 f2bf(float f) {
    union { float f; unsigned u; } v; v.f = f;
    unsigned r = v.u + 0x7FFFu + ((v.u >> 16) & 1u);
    return (u16)(r >> 16);
}
__device__ __forceinline__ float bf2f(u16 b) {
    union { unsigned u; float f; } v; v.u = ((unsigned)b) << 16;
    return v.f;
}

// async global->LDS, 16 bytes per lane (global_load_lds_dwordx4).
__device__ __forceinline__ void gl2lds16(const void* g, void* l) {
    __builtin_amdgcn_global_load_lds(
        (__attribute__((address_space(1))) void*)g,
        (__attribute__((address_space(3))) void*)l,
        16, 0, 0);
}

#define WAITVM(N)  asm volatile("s_waitcnt vmcnt(" #N ")" ::: "memory")
#define WAITLG(N)  asm volatile("s_waitcnt lgkmcnt(" #N ")" ::: "memory")
#define SCHED0()   __builtin_amdgcn_sched_barrier(0)
#define BAR()      __builtin_amdgcn_s_barrier()

// ---------------- cast x fp32 -> bf16, 8 elems/thread ----------------
__global__ __launch_bounds__(256) void cast_f32_bf16(
    const float* __restrict__ in, u16* __restrict__ out, int n8) {
    int i = blockIdx.x * 256 + threadIdx.x;
    if (i >= n8) return;
    const float4* p = (const float4*)in + (size_t)i * 2;
    float4 a = p[0], b = p[1];
    union { u16 u[8]; uint4 v; } r;
    r.u[0] = f2bf(a.x); r.u[1] = f2bf(a.y); r.u[2] = f2bf(a.z); r.u[3] = f2bf(a.w);
    r.u[4] = f2bf(b.x); r.u[5] = f2bf(b.y); r.u[6] = f2bf(b.z); r.u[7] = f2bf(b.w);
    ((uint4*)out)[i] = r.v;
}

// ---------------- NF4 dequant: int32 codes -> bf16, 8 elems/thread ----------
__global__ __launch_bounds__(256) void dequant_nf4(
    const int* __restrict__ q, const float* __restrict__ s,
    u16* __restrict__ w, int I, int spr) {
    __shared__ float tab[16];
    if (threadIdx.x < 16) tab[threadIdx.x] = NF4C[threadIdx.x];
    __syncthreads();
    int col = (blockIdx.x * 256 + threadIdx.x) * 8;
    if (col >= I) return;
    int row = blockIdx.y;
    size_t base = (size_t)row * I + col;
    int4 c0 = *(const int4*)(q + base);
    int4 c1 = *(const int4*)(q + base + 4);
    float sc = s[(size_t)row * spr + (col >> 6)];
    union { u16 u[8]; uint4 v; } r;
    r.u[0] = f2bf(tab[c0.x & 15] * sc);
    r.u[1] = f2bf(tab[c0.y & 15] * sc);
    r.u[2] = f2bf(tab[c0.z & 15] * sc);
    r.u[3] = f2bf(tab[c0.w & 15] * sc);
    r.u[4] = f2bf(tab[c1.x & 15] * sc);
    r.u[5] = f2bf(tab[c1.y & 15] * sc);
    r.u[6] = f2bf(tab[c1.z & 15] * sc);
    r.u[7] = f2bf(tab[c1.w & 15] * sc);
    *(uint4*)(w + base) = r.v;
}

// ---------------- bf16 GEMM, B transposed: C[M,N] = A[M,K] * B[N,K]^T -------
// 256x256 tile, BK=64, 8 waves (2M x 4N), per-wave 128x64 out = acc[8][4].
//
// Round-4: round-2 structure (best so far) with merged phase-pairs.
// Per K-tile T (c=T&1 compile-time via 2-tile unroll), TWO phases:
//  PhA: 16 ds_read (afA: A-quad0, bfA+bfB: all B) ; STG A1,B1(T+1)->o ;
//       lgkmcnt(8) ; bar ; lgkmcnt(0) ; setprio1 ; Q00+Q01 (32 MFMA) ; bar
//  PhB: 8 ds_read (afB: A-quad1) ; STG A0,B0(T+2)->c ; vmcnt(4) ;
//       bar ; lgkmcnt(0) ; setprio1 ; Q10+Q11 (32 MFMA) ; bar
// 4 barriers/K-tile (was 8). vmcnt(4) (was 2): retires exactly A1,B1(T+1)
// (+ leftovers A0,B0(T+1)), leaves A0,B0(T+2) in flight -- no wait on the
// just-issued prefetch. Reads drain same-phase (no cross-barrier register
// liveness -- round-3's regression). lgkmcnt(8) pre-barrier overlaps half
// the 16-read drain with the barrier wait (m201's optional trick).
// WAR chains: every staged region's last ds_read batch drains at a
// lgkmcnt(0) >= 1 barrier before the stage issues (verified per region).
//
// EPI: 0 = store bf16; 1 = store bf16 silu(gate)*acc (gate may alias Cout);
//      2 = store fp32.
template<int EPI>
__global__ __launch_bounds__(512, 2) void gemm_bt(
    const u16* __restrict__ A, const u16* __restrict__ B,
    void* Cout, const u16* gate, int K, int ldc) {
    __shared__ u16 lA[2 * 16384];   // 64 KB: dbuf x (256 rows x 64 K)
    __shared__ u16 lB[2 * 16384];   // 64 KB

    const int tid  = threadIdx.x;
    const int lane = tid & 63;
    const int wv   = tid >> 6;               // 0..7

    // ---- bijective XCD swizzle (nwg % 8 == 0 for all our launches) ----
    const int NT = gridDim.x, MT = gridDim.y;
    int id  = blockIdx.y * NT + blockIdx.x;
    int nid = (id & 7) * ((NT * MT) >> 3) + (id >> 3);
    const int bx = nid / MT;                 // N tile
    const int by = nid - bx * MT;            // M tile

    // ---- staging lane pattern (16B-granule XOR swizzle, verified 0-conflict)
    const int sr = lane >> 2;                        // row within 16-row group
    const int sq = (lane & 3) ^ ((sr >> 1) & 3);     // swizzled 16B granule

    // band groups owned by this wave (16-row groups, 16 per operand)
    const int gA0 = ((wv & 4) << 1) + (wv & 3);      // A quad0: g 0-3, 8-11
    const int gA1 = gA0 + 4;                         // A quad1: g 4-7, 12-15
    const int gB0 = ((wv >> 1) << 2) + (wv & 1);     // B quad0: g bit1 == 0
    const int gB1 = gB0 + 2;                         // B quad1: g bit1 == 1

    const u16* pA0 = A + (size_t)(by * 256 + gA0 * 16 + sr) * K + (sq << 3);
    const u16* pA1 = A + (size_t)(by * 256 + gA1 * 16 + sr) * K + (sq << 3);
    const u16* pB0 = B + (size_t)(bx * 256 + gB0 * 16 + sr) * K + (sq << 3);
    const u16* pB1 = B + (size_t)(bx * 256 + gB1 * 16 + sr) * K + (sq << 3);

    // LDS stage bases (u16 units): sub-tile (g, kslice s) at (s*16+g)*512
    const int sA0 = gA0 * 512 + lane * 8;
    const int sA1 = gA1 * 512 + lane * 8;
    const int sB0 = gB0 * 512 + lane * 8;
    const int sB1 = gB1 * 512 + lane * 8;

    // fragment read offsets (slot16 = 0..63 permutation, 0 conflicts)
    const int r16    = lane & 15;
    const int pq     = lane >> 4;
    const int slot16 = (r16 << 2) + (pq ^ ((r16 >> 1) & 3));
    const int aBase  = ((wv & 1) << 12) + slot16 * 8;   // (wv&1)*8 groups
    const int bBase  = ((wv >> 1) << 11) + slot16 * 8;  // (wv>>1)*4 groups

#define STG_A0(TT, D) do { const u16* g_ = pA0 + (size_t)(TT) * 64;       \
        u16* l_ = lA + ((D) << 14) + sA0;                                 \
        gl2lds16(g_, l_); gl2lds16(g_ + 32, l_ + 8192); } while (0)
#define STG_A1(TT, D) do { const u16* g_ = pA1 + (size_t)(TT) * 64;       \
        u16* l_ = lA + ((D) << 14) + sA1;                                 \
        gl2lds16(g_, l_); gl2lds16(g_ + 32, l_ + 8192); } while (0)
#define STG_B0(TT, D) do { const u16* g_ = pB0 + (size_t)(TT) * 64;       \
        u16* l_ = lB + ((D) << 14) + sB0;                                 \
        gl2lds16(g_, l_); gl2lds16(g_ + 32, l_ + 8192); } while (0)
#define STG_B1(TT, D) do { const u16* g_ = pB1 + (size_t)(TT) * 64;       \
        u16* l_ = lB + ((D) << 14) + sB1;                                 \
        gl2lds16(g_, l_); gl2lds16(g_ + 32, l_ + 8192); } while (0)

    // af[mm*2+s] = A frag (row-group QM*4+mm of wave half, kslice s)
#define DSR_A(C_, QM) do {                                                \
        const u16* b_ = lA + ((C_) << 14) + aBase + (QM) * (4 * 512);     \
        _Pragma("unroll")                                                 \
        for (int mm = 0; mm < 4; ++mm) {                                  \
            af[mm * 2 + 0] = *(const bf16x8*)(b_ + mm * 512);             \
            af[mm * 2 + 1] = *(const bf16x8*)(b_ + mm * 512 + 8192);      \
        } } while (0)
    // bf[(QN*2+jj)*2+s] = B frag (n-frag QN*2+jj, kslice s)
#define DSR_B(C_, QN) do {                                                \
        const u16* b_ = lB + ((C_) << 14) + bBase + (QN) * (2 * 512);     \
        _Pragma("unroll")                                                 \
        for (int jj = 0; jj < 2; ++jj) {                                  \
            bf[(QN) * 4 + jj * 2 + 0] = *(const bf16x8*)(b_ + jj * 512);  \
            bf[(QN) * 4 + jj * 2 + 1] = *(const bf16x8*)(b_ + jj * 512 + 8192); \
        } } while (0)

#define MFMA_Q(QM, QN) do {                                               \
        _Pragma("unroll")                                                 \
        for (int mm = 0; mm < 4; ++mm)                                    \
        _Pragma("unroll")                                                 \
        for (int jj = 0; jj < 2; ++jj) {                                  \
            f32x4 c_ = acc[(QM) * 4 + mm][(QN) * 2 + jj];                 \
            c_ = __builtin_amdgcn_mfma_f32_16x16x32_bf16(                 \
                af[mm * 2 + 0], bf[(QN) * 4 + jj * 2 + 0], c_, 0, 0, 0);  \
            c_ = __builtin_amdgcn_mfma_f32_16x16x32_bf16(                 \
                af[mm * 2 + 1], bf[(QN) * 4 + jj * 2 + 1], c_, 0, 0, 0);  \
            acc[(QM) * 4 + mm][(QN) * 2 + jj] = c_;                       \
        } } while (0)

    // one K-tile: c = LDS buf of tile T_, o = other buf (compile-time)
#define KTILE(T_, C_, O_) do {                                            \
        const int t1_ = ((T_) + 1 < KT) ? (T_) + 1 : KT - 1;              \
        const int t2_ = ((T_) + 2 < KT) ? (T_) + 2 : KT - 1;              \
        /* Phase A: quads (0,0)+(0,1) */                                  \
        DSR_A(C_, 0); DSR_B(C_, 0); DSR_B(C_, 1);                         \
        STG_A1(t1_, O_); STG_B1(t1_, O_);                                 \
        WAITLG(8);                                                        \
        SCHED0(); BAR();                                                  \
        WAITLG(0);                                                        \
        SCHED0();                                                         \
        __builtin_amdgcn_s_setprio(1);                                    \
        MFMA_Q(0, 0); MFMA_Q(0, 1);                                       \
        __builtin_amdgcn_s_setprio(0);                                    \
        SCHED0(); BAR(); SCHED0();                                        \
        /* Phase B: quads (1,0)+(1,1) */                                  \
        DSR_A(C_, 1);                                                     \
        STG_A0(t2_, C_); STG_B0(t2_, C_);                                 \
        WAITVM(4);                                                        \
        SCHED0(); BAR();                                                  \
        WAITLG(0);                                                        \
        SCHED0();                                                         \
        __builtin_amdgcn_s_setprio(1);                                    \
        MFMA_Q(1, 0); MFMA_Q(1, 1);                                       \
        __builtin_amdgcn_s_setprio(0);                                    \
        SCHED0(); BAR(); SCHED0();                                        \
    } while (0)

    f32x4 acc[8][4] = {};
    bf16x8 af[8], bf[8];
    const int KT = K >> 6;                   // K-tiles of 64 (even: 64 / 172)

    // prologue: tile0 fully -> buf0 ; tile1 A0/B0 -> buf1 ; certify tile0
    STG_A0(0, 0); STG_B0(0, 0); STG_A1(0, 0); STG_B1(0, 0);
    STG_A0(1, 1); STG_B0(1, 1);
    WAITVM(4);                               // tile-0's 8 loads retired
    BAR(); SCHED0();

    for (int T = 0; T < KT; T += 2) {
        KTILE(T, 0, 1);
        KTILE(T + 1, 1, 0);
    }

    // epilogue: D row = (lane>>4)*4 + reg, col = lane&15 (measured m89/m91)
    const int en   = lane & 15;
    const int er   = (lane >> 4) << 2;
    const int row0 = by * 256 + ((wv & 1) << 7);
    const int col0 = bx * 256 + ((wv >> 1) << 6);
    #pragma unroll
    for (int i = 0; i < 8; ++i) {
        int rowb = row0 + i * 16 + er;
        #pragma unroll
        for (int j = 0; j < 4; ++j) {
            int col = col0 + j * 16 + en;
            #pragma unroll
            for (int r = 0; r < 4; ++r) {
                size_t idx = (size_t)(rowb + r) * ldc + col;
                float v = acc[i][j][r];
                if (EPI == 0) {
                    ((u16*)Cout)[idx] = f2bf(v);
                } else if (EPI == 1) {
                    float g = bf2f(gate[idx]);
                    float sg = g / (1.0f + __expf(-g));
                    ((u16*)Cout)[idx] = f2bf(sg * v);
                } else {
                    ((float*)Cout)[idx] = v;
                }
            }
        }
    }
#undef STG_A0
#undef STG_A1
#undef STG_B0
#undef STG_B1
#undef DSR_A
#undef DSR_B
#undef MFMA_Q
#undef KTILE
}

extern "C" void kernel_launch(void* const* d_in, const int* in_sizes, int n_in,
                              void* d_out, int out_size, void* d_ws, size_t ws_size,
                              hipStream_t stream) {
    const float* x   = (const float*)d_in[0];
    const int*   w1q = (const int*)d_in[1];
    const float* w1s = (const float*)d_in[2];
    const int*   w2q = (const int*)d_in[3];
    const float* w2s = (const float*)d_in[4];
    const int*   w3q = (const int*)d_in[5];
    const float* w3s = (const float*)d_in[6];
    float* out = (float*)d_out;

    const int M = 4096, D = 4096, H = 11008;

    u16* xb = (u16*)d_ws;                    // M*D bf16      (33.5 MB)
    u16* wb = xb + (size_t)M * D;            // H*D bf16      (90.2 MB, reused w1/w2/w3)
    u16* hb = wb + (size_t)H * D;            // M*H bf16      (90.2 MB, gate then h)

    // 1. x -> bf16
    cast_f32_bf16<<<(M * D / 8 + 255) / 256, 256, 0, stream>>>(x, xb, M * D / 8);

    // 2-3. w1 dequant, gate = x @ w1^T        grid 43x16 = 688 blocks (%8==0)
    dim3 dqg1((D / 8 + 255) / 256, H);
    dequant_nf4<<<dqg1, 256, 0, stream>>>(w1q, w1s, wb, D, D / 64);
    gemm_bt<0><<<dim3(H / 256, M / 256), 512, 0, stream>>>(xb, wb, hb, nullptr, D, H);

    // 4-5. w2 dequant, h = silu(gate) * (x @ w2^T)   (in-place over gate)
    dequant_nf4<<<dqg1, 256, 0, stream>>>(w2q, w2s, wb, D, D / 64);
    gemm_bt<1><<<dim3(H / 256, M / 256), 512, 0, stream>>>(xb, wb, hb, hb, D, H);

    // 6-7. w3 dequant, out = h @ w3^T (fp32)  grid 16x16 = 256 blocks (%8==0)
    dim3 dqg3((H / 8 + 255) / 256, D);
    dequant_nf4<<<dqg3, 256, 0, stream>>>(w3q, w3s, wb, H, H / 64);
    gemm_bt<2><<<dim3(D / 256, M / 256), 512, 0, stream>>>(hb, wb, out, nullptr, H, D);
}